// Round 7
// baseline (626.312 us; speedup 1.0000x reference)
//
#include <hip/hip_runtime.h>
#include <hip/hip_bf16.h>
#include <math.h>

#define B_   4
#define S_   2048
#define D_   1024
#define H_   16
#define HD_  64
#define DFF_ 4096
#define M_   (B_*S_)   // 8192 rows

typedef __bf16 bf16x8 __attribute__((ext_vector_type(8)));
typedef __bf16 bf16x4 __attribute__((ext_vector_type(4)));
typedef float  floatx4 __attribute__((ext_vector_type(4)));

__device__ __forceinline__ float  b2f(__bf16 v) { return (float)v; }
__device__ __forceinline__ __bf16 f2b(float v)  { return (__bf16)v; }

// async global->LDS, 16 bytes per lane. LDS dests MUST be base + lane*16.
__device__ __forceinline__ void async_ld16(const void* g, void* l) {
    __builtin_amdgcn_global_load_lds(
        (const __attribute__((address_space(1))) unsigned int*)g,
        (__attribute__((address_space(3))) unsigned int*)l, 16, 0, 0);
}

// ---------------------------------------------------------------------------
// Transpose + convert + scale: out[c*R + r] = bf16(in[r*C + c] * scale).
// ---------------------------------------------------------------------------
__global__ void transpose_conv_kernel(const float* __restrict__ in,
                                      __bf16* __restrict__ out, int R, int C,
                                      float scale)
{
    __shared__ float t[32][33];
    int c0 = blockIdx.x * 32, r0 = blockIdx.y * 32;
    int tx = threadIdx.x, ty = threadIdx.y;
    for (int i = ty; i < 32; i += 8)
        t[i][tx] = in[(long)(r0 + i) * C + c0 + tx];
    __syncthreads();
    for (int i = ty; i < 32; i += 8)
        out[(long)(c0 + i) * R + r0 + tx] = f2b(t[tx][i] * scale);
}

// bf16 V -> global transposed vtg[b][h][d][s]  (once; frees attn inner loop)
__global__ void vt_transpose_kernel(const __bf16* __restrict__ qkv,
                                    __bf16* __restrict__ vtg)
{
    __shared__ __bf16 t[32][34];
    int b  = blockIdx.z;
    int h  = blockIdx.y >> 1;
    int d0 = (blockIdx.y & 1) * 32;
    int s0 = blockIdx.x * 32;
    int tx = threadIdx.x, ty = threadIdx.y;
    for (int i = ty; i < 32; i += 8)
        t[i][tx] = qkv[(long)(b * S_ + s0 + i) * 3072 + 2048 + h * 64 + d0 + tx];
    __syncthreads();
    for (int i = ty; i < 32; i += 8)
        vtg[((long)(b * H_ + h) * 64 + d0 + i) * S_ + s0 + tx] = t[tx][i];
}

// fp32 -> bf16 elementwise (n multiple of 8)
__global__ void f2b_kernel(const float* __restrict__ in, __bf16* __restrict__ out,
                           long n)
{
    long i = ((long)blockIdx.x * 256 + threadIdx.x) * 8;
    if (i >= n) return;
    float4 a = *(const float4*)&in[i];
    float4 c = *(const float4*)&in[i + 4];
    union { __bf16 h[8]; uint4 u; } p;
    p.h[0] = f2b(a.x); p.h[1] = f2b(a.y); p.h[2] = f2b(a.z); p.h[3] = f2b(a.w);
    p.h[4] = f2b(c.x); p.h[5] = f2b(c.y); p.h[6] = f2b(c.z); p.h[7] = f2b(c.w);
    *(uint4*)&out[i] = p.u;
}

// concat q/k/v biases; q part scaled by 0.125 (score scale folded into Wq,bq)
__global__ void bias_concat_kernel(const float* __restrict__ bq,
                                   const float* __restrict__ bk,
                                   const float* __restrict__ bv,
                                   float* __restrict__ dst)
{
    int i = blockIdx.x * 256 + threadIdx.x;
    if (i >= 3 * D_) return;
    float v = (i < D_) ? bq[i] * 0.125f
            : (i < 2 * D_) ? bk[i - D_] : bv[i - 2 * D_];
    dst[i] = v;
}

// ---------------------------------------------------------------------------
// bf16 MFMA GEMM 128x128 (m97 structure + XOR bank-swizzle): C = A * Bt^T
//   MODE 0: Cb = bf16(acc + bias)
//   MODE 1: Cf = acc + bias + resid       (fp32, feeds LayerNorm)
//   MODE 2: Cb = bf16(gelu(acc + bias))
// Used for QKV (tail-free at 128), attn-out, FFN2.
// ---------------------------------------------------------------------------
template<int MODE>
__global__ __launch_bounds__(256, 2)
void gemm_kernel(const __bf16* __restrict__ A, const __bf16* __restrict__ Bt,
                 const float* __restrict__ bias, const float* __restrict__ resid,
                 float* __restrict__ Cf, __bf16* __restrict__ Cb,
                 int M, int N, int K)
{
    __shared__ __bf16 sA[128 * 64];
    __shared__ __bf16 sB[128 * 64];

    const int tid  = threadIdx.x;
    const int lane = tid & 63;
    const int wave = tid >> 6;
    const int wm   = (wave >> 1) * 64;
    const int wn   = (wave & 1) * 64;
    const long bm  = (long)blockIdx.y * 128;
    const long bn  = (long)blockIdx.x * 128;

    floatx4 acc[4][4];
#pragma unroll
    for (int i = 0; i < 4; ++i)
#pragma unroll
        for (int j = 0; j < 4; ++j)
#pragma unroll
            for (int r = 0; r < 4; ++r) acc[i][j][r] = 0.0f;

    const int mrow = lane & 15;
    const int quad = lane >> 4;
    const int koff0 = ((0 * 4 + quad) ^ (mrow & 7)) * 8;
    const int koff1 = ((1 * 4 + quad) ^ (mrow & 7)) * 8;

    for (int k0 = 0; k0 < K; k0 += 64) {
        __syncthreads();
#pragma unroll
        for (int t = 0; t < 4; ++t) {
            int ci  = tid + t * 256;
            int row = ci >> 3;
            int col = ((ci & 7) ^ (row & 7)) << 3;   // XOR swizzle on global
            async_ld16(A  + (bm + row) * (long)K + k0 + col, &sA[ci * 8]);
            async_ld16(Bt + (bn + row) * (long)K + k0 + col, &sB[ci * 8]);
        }
        __syncthreads();

#pragma unroll
        for (int s = 0; s < 2; ++s) {
            const int ko = s ? koff1 : koff0;
            bf16x8 a[4], b[4];
#pragma unroll
            for (int i = 0; i < 4; ++i)
                a[i] = *(const bf16x8*)&sA[(wm + i * 16 + mrow) * 64 + ko];
#pragma unroll
            for (int j = 0; j < 4; ++j)
                b[j] = *(const bf16x8*)&sB[(wn + j * 16 + mrow) * 64 + ko];
#pragma unroll
            for (int i = 0; i < 4; ++i)
#pragma unroll
                for (int j = 0; j < 4; ++j)
                    acc[i][j] = __builtin_amdgcn_mfma_f32_16x16x32_bf16(
                        a[i], b[j], acc[i][j], 0, 0, 0);
        }
    }

    // D: row = quad*4 + reg, col = lane&15   [verified m89/m91]
    const int rq = quad * 4;
    const int cn = lane & 15;
#pragma unroll
    for (int i = 0; i < 4; ++i) {
#pragma unroll
        for (int j = 0; j < 4; ++j) {
            long col = bn + wn + j * 16 + cn;
            float bv = bias[col];
#pragma unroll
            for (int r = 0; r < 4; ++r) {
                long row = bm + wm + i * 16 + rq + r;
                float v = acc[i][j][r] + bv;
                if (MODE == 0) {
                    Cb[row * N + col] = f2b(v);
                } else if (MODE == 1) {
                    Cf[row * N + col] = v + resid[row * N + col];
                } else {
                    float g = 0.5f * v * (1.0f + erff(v * 0.70710678118654752f));
                    Cb[row * N + col] = f2b(g);
                }
            }
        }
    }
}

// ---------------------------------------------------------------------------
// bf16 MFMA GEMM 256x256, 8 waves (2M x 4N), BK=64, SIMPLE 2-phase dbuf --
// the attn-v4 sync skeleton (proven this session) at 256^2 geometry:
//   prologue: STAGE(tile0); vmcnt(0); barrier
//   loop:     STAGE(buf^1, t+1); ds_read+64 MFMA on buf; vmcnt(0)+barrier
// Per wave per K-tile: 64 MFMA / 24 ds_read_b128 (2.7x better amortization
// than 128^2's 16:8). LDS 128KB -> 1 block/CU, 8 waves = 2/SIMD.
// NOT the failed multi-phase schedule (r2/r4) -- single lgkm wait per
// s-slice, single vmcnt(0) drain per tile, loads have the whole 64-MFMA
// phase to land. Used for FFN1 only (512 blocks = exactly 2 rounds).
// Ledger: buf[cur] ready via prev iter's vmcnt(0)+barrier; buf[cur^1]
// overwrite issued >=1 barrier after its last read (read in iter t-1).
// ---------------------------------------------------------------------------
template<int MODE>
__global__ __launch_bounds__(512, 2)
void gemm256v2_kernel(const __bf16* __restrict__ A, const __bf16* __restrict__ Bt,
                      const float* __restrict__ bias, const float* __restrict__ resid,
                      float* __restrict__ Cf, __bf16* __restrict__ Cb,
                      int M, int N, int K)
{
    __shared__ __bf16 sA[2][256 * 64];
    __shared__ __bf16 sB[2][256 * 64];

    const int tid  = threadIdx.x;
    const int lane = tid & 63;
    const int wave = tid >> 6;
    const int wm   = (wave >> 2) * 128;   // 2 M-groups
    const int wn   = (wave & 3) * 64;     // 4 N-groups
    const long bm  = (long)blockIdx.y * 256;
    const long bn  = (long)blockIdx.x * 256;

    floatx4 acc[8][4];
#pragma unroll
    for (int i = 0; i < 8; ++i)
#pragma unroll
        for (int j = 0; j < 4; ++j)
#pragma unroll
            for (int r = 0; r < 4; ++r) acc[i][j][r] = 0.0f;

    const int mrow = lane & 15;
    const int quad = lane >> 4;

    auto STAGE = [&](int pb, int k0) {
#pragma unroll
        for (int t = 0; t < 4; ++t) {
            int ci  = tid + t * 512;
            int row = ci >> 3;                       // 0..255
            int col = ((ci & 7) ^ (row & 7)) << 3;   // XOR swizzle on global
            async_ld16(A  + (bm + row) * (long)K + k0 + col, &sA[pb][ci * 8]);
            async_ld16(Bt + (bn + row) * (long)K + k0 + col, &sB[pb][ci * 8]);
        }
    };

    // prologue: tile 0
    STAGE(0, 0);
    asm volatile("s_waitcnt vmcnt(0)" ::: "memory");
    __builtin_amdgcn_s_barrier();
    __builtin_amdgcn_sched_barrier(0);

    int cur = 0;
    for (int k0 = 0; k0 < K; k0 += 64) {
        if (k0 + 64 < K) STAGE(cur ^ 1, k0 + 64);

#pragma unroll
        for (int s = 0; s < 2; ++s) {
            bf16x8 a[8], b[4];
#pragma unroll
            for (int i = 0; i < 8; ++i) {
                int rr = wm + i * 16 + mrow;
                int ko = ((s * 4 + quad) ^ (rr & 7)) << 3;
                a[i] = *(const bf16x8*)&sA[cur][rr * 64 + ko];
            }
#pragma unroll
            for (int j = 0; j < 4; ++j) {
                int rr = wn + j * 16 + mrow;
                int ko = ((s * 4 + quad) ^ (rr & 7)) << 3;
                b[j] = *(const bf16x8*)&sB[cur][rr * 64 + ko];
            }
            __builtin_amdgcn_s_setprio(1);
#pragma unroll
            for (int i = 0; i < 8; ++i)
#pragma unroll
                for (int j = 0; j < 4; ++j)
                    acc[i][j] = __builtin_amdgcn_mfma_f32_16x16x32_bf16(
                        a[i], b[j], acc[i][j], 0, 0, 0);
            __builtin_amdgcn_s_setprio(0);
        }

        asm volatile("s_waitcnt vmcnt(0) lgkmcnt(0)" ::: "memory");
        __builtin_amdgcn_s_barrier();
        __builtin_amdgcn_sched_barrier(0);
        cur ^= 1;
    }

    // D: row = quad*4 + reg, col = lane&15   [verified m89/m91]
    const int rq = quad * 4;
    const int cn = lane & 15;
#pragma unroll
    for (int i = 0; i < 8; ++i) {
#pragma unroll
        for (int j = 0; j < 4; ++j) {
            long col = bn + wn + j * 16 + cn;
            float bv = bias[col];
#pragma unroll
            for (int r = 0; r < 4; ++r) {
                long row = bm + wm + i * 16 + rq + r;
                float v = acc[i][j][r] + bv;
                if (MODE == 0) {
                    Cb[row * N + col] = f2b(v);
                } else if (MODE == 1) {
                    Cf[row * N + col] = v + resid[row * N + col];
                } else {
                    float g = 0.5f * v * (1.0f + erff(v * 0.70710678118654752f));
                    Cb[row * N + col] = f2b(g);
                }
            }
        }
    }
}

// ---------------------------------------------------------------------------
// MFMA flash attention v4 (measured best, 136.4us): dbuf K/V, Ps aliases the
// Q staging buffer (40KB LDS), T5 setprio around both MFMA clusters, mask
// software-prefetched one K-tile ahead, one vmcnt(0)+barrier per iteration.
// Falsified alternatives: QBLK=128 (r1, occupancy), single-buffered V (r5,
// extra barrier cost), swapped-QK in-register P (r6, bpermute conflicts).
// ---------------------------------------------------------------------------
__global__ __launch_bounds__(256, 2)
void attn_kernel(const __bf16* __restrict__ QKV, const __bf16* __restrict__ VT,
                 const float* __restrict__ mask, __bf16* __restrict__ ctx)
{
    __shared__ __bf16 Ks[2][64 * 64];  // [buf][key][d]  swizzled chunks
    __shared__ __bf16 Vt[2][64 * 64];  // [buf][d][key]  swizzled chunks
    __shared__ __bf16 Ps[64 * 64];     // [qrow][key]; also Q staging buffer

    const int tid  = threadIdx.x;
    const int lane = tid & 63;
    const int wave = tid >> 6;
    const int w16  = wave * 16;
    const int b    = blockIdx.z, h = blockIdx.y;
    const int q0   = blockIdx.x * 64;
    const int cn   = lane & 15;
    const int quad = lane >> 4;
    const int rq   = quad * 4;
    const int koff0 = ((0 * 4 + quad) ^ (cn & 7)) * 8;
    const int koff1 = ((1 * 4 + quad) ^ (cn & 7)) * 8;

    const long vbase = ((long)(b * H_ + h) * 64) * S_;   // vtg row base

    auto STAGE = [&](int bufi, int k0) {
#pragma unroll
        for (int t = 0; t < 2; ++t) {
            int ci = tid + t * 256;
            int r  = ci >> 3;
            int cz = ((ci & 7) ^ (r & 7)) << 3;
            async_ld16(QKV + (long)(b * S_ + k0 + r) * 3072 + 1024 + h * 64 + cz,
                       &Ks[bufi][ci * 8]);
            async_ld16(VT + vbase + (long)r * S_ + k0 + cz, &Vt[bufi][ci * 8]);
        }
    };

    // ---- prologue: stage Q (into Ps) + tile 0 ----
#pragma unroll
    for (int t = 0; t < 2; ++t) {
        int ci = tid + t * 256;
        int qr = ci >> 3, dc = ((ci & 7) ^ (qr & 7)) << 3;
        async_ld16(QKV + (long)(b * S_ + q0 + qr) * 3072 + h * 64 + dc,
                   &Ps[ci * 8]);
    }
    STAGE(0, 0);
    // prefetch tile-0 mask while loads are in flight
    float mv[4];
#pragma unroll
    for (int jt = 0; jt < 4; ++jt)
        mv[jt] = mask[(long)b * S_ + jt * 16 + cn] - 8.0f;
    asm volatile("s_waitcnt vmcnt(0)" ::: "memory");
    __builtin_amdgcn_s_barrier();
    __builtin_amdgcn_sched_barrier(0);

    // Q fragments (wave-private rows of Ps; Ps reused for P after this)
    const bf16x8 aq0 = *(const bf16x8*)&Ps[(w16 + cn) * 64 + koff0];
    const bf16x8 aq1 = *(const bf16x8*)&Ps[(w16 + cn) * 64 + koff1];

    float l_[4];
    floatx4 o_[4];
#pragma unroll
    for (int r = 0; r < 4; ++r) l_[r] = 0.0f;
#pragma unroll
    for (int jt = 0; jt < 4; ++jt)
#pragma unroll
        for (int r = 0; r < 4; ++r) o_[jt][r] = 0.0f;

    int cur = 0;
    for (int k0 = 0; k0 < S_; k0 += 64) {
        // issue next tile's loads (buf[cur^1] last read ended >=1 barrier ago)
        float mvn[4];
        if (k0 + 64 < S_) {
            STAGE(cur ^ 1, k0 + 64);
#pragma unroll
            for (int jt = 0; jt < 4; ++jt)
                mvn[jt] = mask[(long)b * S_ + k0 + 64 + jt * 16 + cn] - 8.0f;
        }

        // ---- S = Q K^T ----  (buf[cur] landed: prev iter's vmcnt(0)+barrier)
        floatx4 st[4];
#pragma unroll
        for (int jt = 0; jt < 4; ++jt)
#pragma unroll
            for (int r = 0; r < 4; ++r) st[jt][r] = 0.0f;
        __builtin_amdgcn_s_setprio(1);
#pragma unroll
        for (int jt = 0; jt < 4; ++jt) {
            bf16x8 b0 = *(const bf16x8*)&Ks[cur][(jt * 16 + cn) * 64 + koff0];
            bf16x8 b1 = *(const bf16x8*)&Ks[cur][(jt * 16 + cn) * 64 + koff1];
            st[jt] = __builtin_amdgcn_mfma_f32_16x16x32_bf16(aq0, b0, st[jt], 0, 0, 0);
            st[jt] = __builtin_amdgcn_mfma_f32_16x16x32_bf16(aq1, b1, st[jt], 0, 0, 0);
        }
        __builtin_amdgcn_s_setprio(0);
        // ---- p = exp(s + mask - 8); per-lane partial row sums ----
#pragma unroll
        for (int jt = 0; jt < 4; ++jt) {
#pragma unroll
            for (int r = 0; r < 4; ++r) {
                float p = __expf(st[jt][r] + mv[jt]);
                st[jt][r] = p;
                l_[r] += p;
            }
        }
        // ---- P -> LDS (wave-private rows; DS pipe in-order per wave) ----
#pragma unroll
        for (int jt = 0; jt < 4; ++jt)
#pragma unroll
            for (int r = 0; r < 4; ++r) {
                int prow = w16 + rq + r;
                int pcol = (((jt * 2 + (cn >> 3)) ^ (prow & 7)) << 3) + (cn & 7);
                Ps[prow * 64 + pcol] = f2b(st[jt][r]);
            }

        // ---- O += P V ----
        {
            bf16x8 ap0 = *(const bf16x8*)&Ps[(w16 + cn) * 64 + koff0];
            bf16x8 ap1 = *(const bf16x8*)&Ps[(w16 + cn) * 64 + koff1];
            __builtin_amdgcn_s_setprio(1);
#pragma unroll
            for (int jt = 0; jt < 4; ++jt) {
                bf16x8 b0 = *(const bf16x8*)&Vt[cur][(jt * 16 + cn) * 64 + koff0];
                bf16x8 b1 = *(const bf16x8*)&Vt[cur][(jt * 16 + cn) * 64 + koff1];
                o_[jt] = __builtin_amdgcn_mfma_f32_16x16x32_bf16(ap0, b0, o_[jt], 0, 0, 0);
                o_[jt] = __builtin_amdgcn_mfma_f32_16x16x32_bf16(ap1, b1, o_[jt], 0, 0, 0);
            }
            __builtin_amdgcn_s_setprio(0);
        }

        // next tile's loads had the whole compute phase to land; drain + sync
        asm volatile("s_waitcnt vmcnt(0) lgkmcnt(0)" ::: "memory");
        __builtin_amdgcn_s_barrier();
        __builtin_amdgcn_sched_barrier(0);
        if (k0 + 64 < S_) {
#pragma unroll
            for (int jt = 0; jt < 4; ++jt) mv[jt] = mvn[jt];
        }
        cur ^= 1;
    }

    // final row-sum reduce + normalize + store
#pragma unroll
    for (int r = 0; r < 4; ++r) {
        float l = l_[r];
        l += __shfl_xor(l, 1);
        l += __shfl_xor(l, 2);
        l += __shfl_xor(l, 4);
        l += __shfl_xor(l, 8);
        float linv = 1.0f / l;
        long rowg = (long)(b * S_ + q0 + w16 + rq + r) * D_ + h * 64;
#pragma unroll
        for (int jt = 0; jt < 4; ++jt)
            ctx[rowg + jt * 16 + cn] = f2b(o_[jt][r] * linv);
    }
}

// ---------------------------------------------------------------------------
// Row LayerNorm, row length 1024. Writes fp32 out and (optionally) bf16 copy.
// ---------------------------------------------------------------------------
__global__ __launch_bounds__(256)
void ln_kernel(const float* __restrict__ X, const float* __restrict__ gamma,
               const float* __restrict__ beta, float* __restrict__ out,
               __bf16* __restrict__ outb)
{
    const long row = blockIdx.x;
    const int tid = threadIdx.x;
    const float* x = X + row * D_;
    float4 v = *(const float4*)&x[tid * 4];
    float s  = v.x + v.y + v.z + v.w;
    float s2 = v.x * v.x + v.y * v.y + v.z * v.z + v.w * v.w;
    for (int off = 32; off > 0; off >>= 1) {
        s  += __shfl_down(s, off);
        s2 += __shfl_down(s2, off);
    }
    __shared__ float red[8];
    int wave = tid >> 6, lane = tid & 63;
    if (lane == 0) { red[wave] = s; red[4 + wave] = s2; }
    __syncthreads();
    float ts  = red[0] + red[1] + red[2] + red[3];
    float ts2 = red[4] + red[5] + red[6] + red[7];
    float mu  = ts * (1.0f / D_);
    float var = ts2 * (1.0f / D_) - mu * mu;
    float rs  = rsqrtf(fmaxf(var, 0.0f) + 1e-12f);
    float4 g = *(const float4*)&gamma[tid * 4];
    float4 b = *(const float4*)&beta[tid * 4];
    float4 o;
    o.x = (v.x - mu) * rs * g.x + b.x;
    o.y = (v.y - mu) * rs * g.y + b.y;
    o.z = (v.z - mu) * rs * g.z + b.z;
    o.w = (v.w - mu) * rs * g.w + b.w;
    *(float4*)&out[row * D_ + tid * 4] = o;
    if (outb) {
        bf16x4 ob;
        ob[0] = f2b(o.x); ob[1] = f2b(o.y); ob[2] = f2b(o.z); ob[3] = f2b(o.w);
        *(bf16x4*)&outb[row * D_ + tid * 4] = ob;
    }
}

// ---------------------------------------------------------------------------
extern "C" void kernel_launch(void* const* d_in, const int* in_sizes, int n_in,
                              void* d_out, int out_size, void* d_ws, size_t ws_size,
                              hipStream_t stream)
{
    const float* hid  = (const float*)d_in[0];
    const float* mask = (const float*)d_in[1];
    const float* Wq   = (const float*)d_in[2];
    const float* bq   = (const float*)d_in[3];
    const float* Wk   = (const float*)d_in[4];
    const float* bk   = (const float*)d_in[5];
    const float* Wv   = (const float*)d_in[6];
    const float* bv   = (const float*)d_in[7];
    const float* Wo   = (const float*)d_in[8];
    const float* bo   = (const float*)d_in[9];
    const float* g1   = (const float*)d_in[10];
    const float* b1   = (const float*)d_in[11];
    const float* Wi   = (const float*)d_in[12];
    const float* bi   = (const float*)d_in[13];
    const float* Wo2  = (const float*)d_in[14];
    const float* bo2  = (const float*)d_in[15];
    const float* g2   = (const float*)d_in[16];
    const float* b2   = (const float*)d_in[17];
    float* out = (float*)d_out;

    char* w = (char*)d_ws;
    auto take = [&](size_t bytes) { char* p = w; w += bytes; return p; };
    __bf16* wqkvb = (__bf16*)take((size_t)3 * D_ * D_ * 2);  // [3072][1024]
    __bf16* wob   = (__bf16*)take((size_t)D_ * D_ * 2);
    __bf16* wib   = (__bf16*)take((size_t)D_ * DFF_ * 2);
    __bf16* wo2b  = (__bf16*)take((size_t)D_ * DFF_ * 2);
    float*  qkvbias = (float*)take(16384);
    __bf16* qkv   = (__bf16*)take((size_t)M_ * 3 * D_ * 2);  // 48MB
    __bf16* ctxb  = (__bf16*)take((size_t)M_ * D_ * 2);      // 16MB
    __bf16* hb    = (__bf16*)take((size_t)M_ * D_ * 2);      // 16MB
    float*  tmp      = (float*)take((size_t)M_ * D_ * 4);
    float*  attn_out = (float*)take((size_t)M_ * D_ * 4);
    // aliases (regions dead by the time these are used):
    __bf16* hbuf = qkv;       // FFN hidden [M][4096] = 64MB over qkv+ctxb
    __bf16* vtg  = hb;        // hb dead after QKV GEMM; vtg dead after attn
    __bf16* attn_out_b = hb;  // written at ln1 (after attn)
    (void)in_sizes; (void)n_in; (void)out_size; (void)ws_size;

    dim3 tb(32, 8);
    transpose_conv_kernel<<<dim3(D_/32, D_/32), tb, 0, stream>>>(Wq, wqkvb,            D_, D_, 0.125f);
    transpose_conv_kernel<<<dim3(D_/32, D_/32), tb, 0, stream>>>(Wk, wqkvb + D_*D_,    D_, D_, 1.0f);
    transpose_conv_kernel<<<dim3(D_/32, D_/32), tb, 0, stream>>>(Wv, wqkvb + 2*D_*D_,  D_, D_, 1.0f);
    transpose_conv_kernel<<<dim3(D_/32, D_/32), tb, 0, stream>>>(Wo, wob, D_, D_, 1.0f);
    transpose_conv_kernel<<<dim3(DFF_/32, D_/32), tb, 0, stream>>>(Wi, wib, D_, DFF_, 1.0f);
    transpose_conv_kernel<<<dim3(D_/32, DFF_/32), tb, 0, stream>>>(Wo2, wo2b, DFF_, D_, 1.0f);
    bias_concat_kernel<<<12, 256, 0, stream>>>(bq, bk, bv, qkvbias);
    f2b_kernel<<<(M_*D_/8 + 255)/256, 256, 0, stream>>>(hid, hb, (long)M_*D_);

    // fused QKV projection: [8192,1024] x [1024,3072]
    gemm_kernel<0><<<dim3(3*D_/128, M_/128), 256, 0, stream>>>(
        hb, wqkvb, qkvbias, nullptr, nullptr, qkv, M_, 3*D_, D_);

    // V -> vtg[b][h][d][s]
    vt_transpose_kernel<<<dim3(S_/32, H_*2, B_), tb, 0, stream>>>(qkv, vtg);

    attn_kernel<<<dim3(S_/64, H_, B_), 256, 0, stream>>>(qkv, vtg, mask, ctxb);

    // attn out projection + residual (fp32 hid) -> tmp
    gemm_kernel<1><<<dim3(D_/128, M_/128), 256, 0, stream>>>(
        ctxb, wob, bo, hid, tmp, nullptr, M_, D_, D_);
    ln_kernel<<<M_, 256, 0, stream>>>(tmp, g1, b1, attn_out, attn_out_b);

    // FFN1: [8192,1024] x [1024,4096] gelu  (256^2 2-phase; 512 blocks = 2 rounds)
    gemm256v2_kernel<2><<<dim3(DFF_/256, M_/256), 512, 0, stream>>>(
        attn_out_b, wib, bi, nullptr, nullptr, hbuf, M_, DFF_, D_);
    // FFN2: N=1024 -> 128^2 kernel
    gemm_kernel<1><<<dim3(D_/128, M_/128), 256, 0, stream>>>(
        hbuf, wo2b, bo2, attn_out, tmp, nullptr, M_, D_, DFF_);
    ln_kernel<<<M_, 256, 0, stream>>>(tmp, g2, b2, out, nullptr);
}

// Round 8
// 547.428 us; speedup vs baseline: 1.1441x; 1.1441x over previous
//
#include <hip/hip_runtime.h>
#include <hip/hip_bf16.h>
#include <math.h>

#define B_   4
#define S_   2048
#define D_   1024
#define H_   16
#define HD_  64
#define DFF_ 4096
#define M_   (B_*S_)   // 8192 rows

typedef __bf16 bf16x8 __attribute__((ext_vector_type(8)));
typedef __bf16 bf16x4 __attribute__((ext_vector_type(4)));
typedef float  floatx4 __attribute__((ext_vector_type(4)));

__device__ __forceinline__ float  b2f(__bf16 v) { return (float)v; }
__device__ __forceinline__ __bf16 f2b(float v)  { return (__bf16)v; }

// async global->LDS, 16 bytes per lane. LDS dests MUST be base + lane*16.
__device__ __forceinline__ void async_ld16(const void* g, void* l) {
    __builtin_amdgcn_global_load_lds(
        (const __attribute__((address_space(1))) unsigned int*)g,
        (__attribute__((address_space(3))) unsigned int*)l, 16, 0, 0);
}

// ---------------------------------------------------------------------------
// Fused prep: all 6 weight transposes + bias concat + hidden f2b in ONE
// launch (was 8 small serial launches; saves per-launch ramp/drain gaps).
// Segments by blockIdx.x:
//   [0,12288)      weight transpose+convert (Wq/Wk/Wv/Wo: 1024 blocks each;
//                  Wi: 4096; Wo2: 4096), identical math to the old
//                  transpose_conv_kernel.
//   [12288,16384)  f2b of hidden states (4096 blocks x 256 lanes x 8 elems)
//   [16384,16396)  qkv bias concat (q part scaled by 0.125)
// ---------------------------------------------------------------------------
__global__ __launch_bounds__(256)
void prep_kernel(const float* __restrict__ Wq, const float* __restrict__ Wk,
                 const float* __restrict__ Wv, const float* __restrict__ Wo,
                 const float* __restrict__ Wi, const float* __restrict__ Wo2,
                 const float* __restrict__ bq, const float* __restrict__ bk,
                 const float* __restrict__ bv, const float* __restrict__ hid,
                 __bf16* __restrict__ wqkvb, __bf16* __restrict__ wob,
                 __bf16* __restrict__ wib, __bf16* __restrict__ wo2b,
                 float* __restrict__ qkvbias, __bf16* __restrict__ hb)
{
    __shared__ float t[32][33];
    const int bid = blockIdx.x;
    const int tid = threadIdx.x;

    if (bid < 12288) {
        const float* in; __bf16* outp; int R, C, nx, lid; float scale = 1.0f;
        if (bid < 1024)      { in = Wq;  outp = wqkvb;           R = D_;   C = D_;   nx = 32;  lid = bid;        scale = 0.125f; }
        else if (bid < 2048) { in = Wk;  outp = wqkvb + D_*D_;   R = D_;   C = D_;   nx = 32;  lid = bid - 1024; }
        else if (bid < 3072) { in = Wv;  outp = wqkvb + 2*D_*D_; R = D_;   C = D_;   nx = 32;  lid = bid - 2048; }
        else if (bid < 4096) { in = Wo;  outp = wob;             R = D_;   C = D_;   nx = 32;  lid = bid - 3072; }
        else if (bid < 8192) { in = Wi;  outp = wib;             R = D_;   C = DFF_; nx = 128; lid = bid - 4096; }
        else                 { in = Wo2; outp = wo2b;            R = DFF_; C = D_;   nx = 32;  lid = bid - 8192; }
        const int c0 = (lid % nx) * 32, r0 = (lid / nx) * 32;
        const int tx = tid & 31, ty = tid >> 5;
        for (int i = ty; i < 32; i += 8)
            t[i][tx] = in[(long)(r0 + i) * C + c0 + tx];
        __syncthreads();
        for (int i = ty; i < 32; i += 8)
            outp[(long)(c0 + i) * R + r0 + tx] = f2b(t[tx][i] * scale);
    } else if (bid < 16384) {
        long i = ((long)(bid - 12288) * 256 + tid) * 8;
        if (i >= (long)M_ * D_) return;
        float4 a = *(const float4*)&hid[i];
        float4 c = *(const float4*)&hid[i + 4];
        union { __bf16 h[8]; uint4 u; } p;
        p.h[0] = f2b(a.x); p.h[1] = f2b(a.y); p.h[2] = f2b(a.z); p.h[3] = f2b(a.w);
        p.h[4] = f2b(c.x); p.h[5] = f2b(c.y); p.h[6] = f2b(c.z); p.h[7] = f2b(c.w);
        *(uint4*)&hb[i] = p.u;
    } else {
        int i = (bid - 16384) * 256 + tid;
        if (i >= 3 * D_) return;
        float v = (i < D_) ? bq[i] * 0.125f
                : (i < 2 * D_) ? bk[i - D_] : bv[i - 2 * D_];
        qkvbias[i] = v;
    }
}

// bf16 V -> global transposed vtg[b][h][d][s]  (once; frees attn inner loop)
__global__ void vt_transpose_kernel(const __bf16* __restrict__ qkv,
                                    __bf16* __restrict__ vtg)
{
    __shared__ __bf16 t[32][34];
    int b  = blockIdx.z;
    int h  = blockIdx.y >> 1;
    int d0 = (blockIdx.y & 1) * 32;
    int s0 = blockIdx.x * 32;
    int tx = threadIdx.x, ty = threadIdx.y;
    for (int i = ty; i < 32; i += 8)
        t[i][tx] = qkv[(long)(b * S_ + s0 + i) * 3072 + 2048 + h * 64 + d0 + tx];
    __syncthreads();
    for (int i = ty; i < 32; i += 8)
        vtg[((long)(b * H_ + h) * 64 + d0 + i) * S_ + s0 + tx] = t[tx][i];
}

// ---------------------------------------------------------------------------
// bf16 MFMA GEMM 128x128 (m97 structure + XOR bank-swizzle): C = A * Bt^T
//   MODE 0: Cb = bf16(acc + bias)
//   MODE 1: Cf = acc + bias + resid       (fp32, feeds LayerNorm)
//   MODE 2: Cb = bf16(gelu(acc + bias))
// 256^2 ports tested three times (r2, r4, r7): regressed every time.
// 128^2 is this session's GEMM structure.
// ---------------------------------------------------------------------------
template<int MODE>
__global__ __launch_bounds__(256, 2)
void gemm_kernel(const __bf16* __restrict__ A, const __bf16* __restrict__ Bt,
                 const float* __restrict__ bias, const float* __restrict__ resid,
                 float* __restrict__ Cf, __bf16* __restrict__ Cb,
                 int M, int N, int K)
{
    __shared__ __bf16 sA[128 * 64];
    __shared__ __bf16 sB[128 * 64];

    const int tid  = threadIdx.x;
    const int lane = tid & 63;
    const int wave = tid >> 6;
    const int wm   = (wave >> 1) * 64;
    const int wn   = (wave & 1) * 64;
    const long bm  = (long)blockIdx.y * 128;
    const long bn  = (long)blockIdx.x * 128;

    floatx4 acc[4][4];
#pragma unroll
    for (int i = 0; i < 4; ++i)
#pragma unroll
        for (int j = 0; j < 4; ++j)
#pragma unroll
            for (int r = 0; r < 4; ++r) acc[i][j][r] = 0.0f;

    const int mrow = lane & 15;
    const int quad = lane >> 4;
    const int koff0 = ((0 * 4 + quad) ^ (mrow & 7)) * 8;
    const int koff1 = ((1 * 4 + quad) ^ (mrow & 7)) * 8;

    for (int k0 = 0; k0 < K; k0 += 64) {
        __syncthreads();
#pragma unroll
        for (int t = 0; t < 4; ++t) {
            int ci  = tid + t * 256;
            int row = ci >> 3;
            int col = ((ci & 7) ^ (row & 7)) << 3;   // XOR swizzle on global
            async_ld16(A  + (bm + row) * (long)K + k0 + col, &sA[ci * 8]);
            async_ld16(Bt + (bn + row) * (long)K + k0 + col, &sB[ci * 8]);
        }
        __syncthreads();

#pragma unroll
        for (int s = 0; s < 2; ++s) {
            const int ko = s ? koff1 : koff0;
            bf16x8 a[4], b[4];
#pragma unroll
            for (int i = 0; i < 4; ++i)
                a[i] = *(const bf16x8*)&sA[(wm + i * 16 + mrow) * 64 + ko];
#pragma unroll
            for (int j = 0; j < 4; ++j)
                b[j] = *(const bf16x8*)&sB[(wn + j * 16 + mrow) * 64 + ko];
#pragma unroll
            for (int i = 0; i < 4; ++i)
#pragma unroll
                for (int j = 0; j < 4; ++j)
                    acc[i][j] = __builtin_amdgcn_mfma_f32_16x16x32_bf16(
                        a[i], b[j], acc[i][j], 0, 0, 0);
        }
    }

    // D: row = quad*4 + reg, col = lane&15   [verified m89/m91]
    const int rq = quad * 4;
    const int cn = lane & 15;
#pragma unroll
    for (int i = 0; i < 4; ++i) {
#pragma unroll
        for (int j = 0; j < 4; ++j) {
            long col = bn + wn + j * 16 + cn;
            float bv = bias[col];
#pragma unroll
            for (int r = 0; r < 4; ++r) {
                long row = bm + wm + i * 16 + rq + r;
                float v = acc[i][j][r] + bv;
                if (MODE == 0) {
                    Cb[row * N + col] = f2b(v);
                } else if (MODE == 1) {
                    Cf[row * N + col] = v + resid[row * N + col];
                } else {
                    float g = 0.5f * v * (1.0f + erff(v * 0.70710678118654752f));
                    Cb[row * N + col] = f2b(g);
                }
            }
        }
    }
}

// ---------------------------------------------------------------------------
// MFMA flash attention v7 = v4 (measured best, 136.4us: dbuf K/V, Ps aliases
// Q stage, 40KB LDS, setprio, mask prefetch, 1 barrier/iter) + XCD-locality
// block remap: flat 2048-block grid; i&7 selects the XCD slot (HW dispatches
// block i to XCD i%8), and each head's 32 q-blocks all carry the same i&7 ->
// one head's K/V (512KB) lives in ONE XCD's L2 instead of 8. Attacks the
// 139MB FETCH (~3x K/V over-fetch): per-iter vmcnt(0) drain stalls ~300cy
// on HBM-miss stages; with locality they become L2 hits.
// Mapping (bijective): xcd=i&7, t=i>>3; head_lin=xcd*8+(t>>5); q0=(t&31)*64;
// b=head_lin>>4, h=head_lin&15.
// ---------------------------------------------------------------------------
__global__ __launch_bounds__(256, 2)
void attn_kernel(const __bf16* __restrict__ QKV, const __bf16* __restrict__ VT,
                 const float* __restrict__ mask, __bf16* __restrict__ ctx)
{
    __shared__ __bf16 Ks[2][64 * 64];  // [buf][key][d]  swizzled chunks
    __shared__ __bf16 Vt[2][64 * 64];  // [buf][d][key]  swizzled chunks
    __shared__ __bf16 Ps[64 * 64];     // [qrow][key]; also Q staging buffer

    const int tid  = threadIdx.x;
    const int lane = tid & 63;
    const int wave = tid >> 6;
    const int w16  = wave * 16;

    // XCD-locality remap (one head per XCD)
    const int ibk  = blockIdx.x;
    const int xcd  = ibk & 7;
    const int tt   = ibk >> 3;                 // 0..255
    const int head_lin = xcd * 8 + (tt >> 5);  // 0..63
    const int q0   = (tt & 31) * 64;
    const int b    = head_lin >> 4;
    const int h    = head_lin & 15;

    const int cn   = lane & 15;
    const int quad = lane >> 4;
    const int rq   = quad * 4;
    const int koff0 = ((0 * 4 + quad) ^ (cn & 7)) * 8;
    const int koff1 = ((1 * 4 + quad) ^ (cn & 7)) * 8;

    const long vbase = ((long)(b * H_ + h) * 64) * S_;   // vtg row base

    auto STAGE = [&](int bufi, int k0) {
#pragma unroll
        for (int t = 0; t < 2; ++t) {
            int ci = tid + t * 256;
            int r  = ci >> 3;
            int cz = ((ci & 7) ^ (r & 7)) << 3;
            async_ld16(QKV + (long)(b * S_ + k0 + r) * 3072 + 1024 + h * 64 + cz,
                       &Ks[bufi][ci * 8]);
            async_ld16(VT + vbase + (long)r * S_ + k0 + cz, &Vt[bufi][ci * 8]);
        }
    };

    // ---- prologue: stage Q (into Ps) + tile 0 ----
#pragma unroll
    for (int t = 0; t < 2; ++t) {
        int ci = tid + t * 256;
        int qr = ci >> 3, dc = ((ci & 7) ^ (qr & 7)) << 3;
        async_ld16(QKV + (long)(b * S_ + q0 + qr) * 3072 + h * 64 + dc,
                   &Ps[ci * 8]);
    }
    STAGE(0, 0);
    // prefetch tile-0 mask while loads are in flight
    float mv[4];
#pragma unroll
    for (int jt = 0; jt < 4; ++jt)
        mv[jt] = mask[(long)b * S_ + jt * 16 + cn] - 8.0f;
    asm volatile("s_waitcnt vmcnt(0)" ::: "memory");
    __builtin_amdgcn_s_barrier();
    __builtin_amdgcn_sched_barrier(0);

    // Q fragments (wave-private rows of Ps; Ps reused for P after this)
    const bf16x8 aq0 = *(const bf16x8*)&Ps[(w16 + cn) * 64 + koff0];
    const bf16x8 aq1 = *(const bf16x8*)&Ps[(w16 + cn) * 64 + koff1];

    float l_[4];
    floatx4 o_[4];
#pragma unroll
    for (int r = 0; r < 4; ++r) l_[r] = 0.0f;
#pragma unroll
    for (int jt = 0; jt < 4; ++jt)
#pragma unroll
        for (int r = 0; r < 4; ++r) o_[jt][r] = 0.0f;

    int cur = 0;
    for (int k0 = 0; k0 < S_; k0 += 64) {
        // issue next tile's loads (buf[cur^1] last read ended >=1 barrier ago)
        float mvn[4];
        if (k0 + 64 < S_) {
            STAGE(cur ^ 1, k0 + 64);
#pragma unroll
            for (int jt = 0; jt < 4; ++jt)
                mvn[jt] = mask[(long)b * S_ + k0 + 64 + jt * 16 + cn] - 8.0f;
        }

        // ---- S = Q K^T ----  (buf[cur] landed: prev iter's vmcnt(0)+barrier)
        floatx4 st[4];
#pragma unroll
        for (int jt = 0; jt < 4; ++jt)
#pragma unroll
            for (int r = 0; r < 4; ++r) st[jt][r] = 0.0f;
        __builtin_amdgcn_s_setprio(1);
#pragma unroll
        for (int jt = 0; jt < 4; ++jt) {
            bf16x8 b0 = *(const bf16x8*)&Ks[cur][(jt * 16 + cn) * 64 + koff0];
            bf16x8 b1 = *(const bf16x8*)&Ks[cur][(jt * 16 + cn) * 64 + koff1];
            st[jt] = __builtin_amdgcn_mfma_f32_16x16x32_bf16(aq0, b0, st[jt], 0, 0, 0);
            st[jt] = __builtin_amdgcn_mfma_f32_16x16x32_bf16(aq1, b1, st[jt], 0, 0, 0);
        }
        __builtin_amdgcn_s_setprio(0);
        // ---- p = exp(s + mask - 8); per-lane partial row sums ----
#pragma unroll
        for (int jt = 0; jt < 4; ++jt) {
#pragma unroll
            for (int r = 0; r < 4; ++r) {
                float p = __expf(st[jt][r] + mv[jt]);
                st[jt][r] = p;
                l_[r] += p;
            }
        }
        // ---- P -> LDS (wave-private rows; DS pipe in-order per wave) ----
#pragma unroll
        for (int jt = 0; jt < 4; ++jt)
#pragma unroll
            for (int r = 0; r < 4; ++r) {
                int prow = w16 + rq + r;
                int pcol = (((jt * 2 + (cn >> 3)) ^ (prow & 7)) << 3) + (cn & 7);
                Ps[prow * 64 + pcol] = f2b(st[jt][r]);
            }

        // ---- O += P V ----
        {
            bf16x8 ap0 = *(const bf16x8*)&Ps[(w16 + cn) * 64 + koff0];
            bf16x8 ap1 = *(const bf16x8*)&Ps[(w16 + cn) * 64 + koff1];
            __builtin_amdgcn_s_setprio(1);
#pragma unroll
            for (int jt = 0; jt < 4; ++jt) {
                bf16x8 b0 = *(const bf16x8*)&Vt[cur][(jt * 16 + cn) * 64 + koff0];
                bf16x8 b1 = *(const bf16x8*)&Vt[cur][(jt * 16 + cn) * 64 + koff1];
                o_[jt] = __builtin_amdgcn_mfma_f32_16x16x32_bf16(ap0, b0, o_[jt], 0, 0, 0);
                o_[jt] = __builtin_amdgcn_mfma_f32_16x16x32_bf16(ap1, b1, o_[jt], 0, 0, 0);
            }
            __builtin_amdgcn_s_setprio(0);
        }

        // next tile's loads had the whole compute phase to land; drain + sync
        asm volatile("s_waitcnt vmcnt(0) lgkmcnt(0)" ::: "memory");
        __builtin_amdgcn_s_barrier();
        __builtin_amdgcn_sched_barrier(0);
        if (k0 + 64 < S_) {
#pragma unroll
            for (int jt = 0; jt < 4; ++jt) mv[jt] = mvn[jt];
        }
        cur ^= 1;
    }

    // final row-sum reduce + normalize + store
#pragma unroll
    for (int r = 0; r < 4; ++r) {
        float l = l_[r];
        l += __shfl_xor(l, 1);
        l += __shfl_xor(l, 2);
        l += __shfl_xor(l, 4);
        l += __shfl_xor(l, 8);
        float linv = 1.0f / l;
        long rowg = (long)(b * S_ + q0 + w16 + rq + r) * D_ + h * 64;
#pragma unroll
        for (int jt = 0; jt < 4; ++jt)
            ctx[rowg + jt * 16 + cn] = f2b(o_[jt][r] * linv);
    }
}

// ---------------------------------------------------------------------------
// Row LayerNorm, row length 1024. Writes fp32 out and (optionally) bf16 copy.
// ---------------------------------------------------------------------------
__global__ __launch_bounds__(256)
void ln_kernel(const float* __restrict__ X, const float* __restrict__ gamma,
               const float* __restrict__ beta, float* __restrict__ out,
               __bf16* __restrict__ outb)
{
    const long row = blockIdx.x;
    const int tid = threadIdx.x;
    const float* x = X + row * D_;
    float4 v = *(const float4*)&x[tid * 4];
    float s  = v.x + v.y + v.z + v.w;
    float s2 = v.x * v.x + v.y * v.y + v.z * v.z + v.w * v.w;
    for (int off = 32; off > 0; off >>= 1) {
        s  += __shfl_down(s, off);
        s2 += __shfl_down(s2, off);
    }
    __shared__ float red[8];
    int wave = tid >> 6, lane = tid & 63;
    if (lane == 0) { red[wave] = s; red[4 + wave] = s2; }
    __syncthreads();
    float ts  = red[0] + red[1] + red[2] + red[3];
    float ts2 = red[4] + red[5] + red[6] + red[7];
    float mu  = ts * (1.0f / D_);
    float var = ts2 * (1.0f / D_) - mu * mu;
    float rs  = rsqrtf(fmaxf(var, 0.0f) + 1e-12f);
    float4 g = *(const float4*)&gamma[tid * 4];
    float4 b = *(const float4*)&beta[tid * 4];
    float4 o;
    o.x = (v.x - mu) * rs * g.x + b.x;
    o.y = (v.y - mu) * rs * g.y + b.y;
    o.z = (v.z - mu) * rs * g.z + b.z;
    o.w = (v.w - mu) * rs * g.w + b.w;
    *(float4*)&out[row * D_ + tid * 4] = o;
    if (outb) {
        bf16x4 ob;
        ob[0] = f2b(o.x); ob[1] = f2b(o.y); ob[2] = f2b(o.z); ob[3] = f2b(o.w);
        *(bf16x4*)&outb[row * D_ + tid * 4] = ob;
    }
}

// ---------------------------------------------------------------------------
extern "C" void kernel_launch(void* const* d_in, const int* in_sizes, int n_in,
                              void* d_out, int out_size, void* d_ws, size_t ws_size,
                              hipStream_t stream)
{
    const float* hid  = (const float*)d_in[0];
    const float* mask = (const float*)d_in[1];
    const float* Wq   = (const float*)d_in[2];
    const float* bq   = (const float*)d_in[3];
    const float* Wk   = (const float*)d_in[4];
    const float* bk   = (const float*)d_in[5];
    const float* Wv   = (const float*)d_in[6];
    const float* bv   = (const float*)d_in[7];
    const float* Wo   = (const float*)d_in[8];
    const float* bo   = (const float*)d_in[9];
    const float* g1   = (const float*)d_in[10];
    const float* b1   = (const float*)d_in[11];
    const float* Wi   = (const float*)d_in[12];
    const float* bi   = (const float*)d_in[13];
    const float* Wo2  = (const float*)d_in[14];
    const float* bo2  = (const float*)d_in[15];
    const float* g2   = (const float*)d_in[16];
    const float* b2   = (const float*)d_in[17];
    float* out = (float*)d_out;

    char* w = (char*)d_ws;
    auto take = [&](size_t bytes) { char* p = w; w += bytes; return p; };
    __bf16* wqkvb = (__bf16*)take((size_t)3 * D_ * D_ * 2);  // [3072][1024]
    __bf16* wob   = (__bf16*)take((size_t)D_ * D_ * 2);
    __bf16* wib   = (__bf16*)take((size_t)D_ * DFF_ * 2);
    __bf16* wo2b  = (__bf16*)take((size_t)D_ * DFF_ * 2);
    float*  qkvbias = (float*)take(16384);
    __bf16* qkv   = (__bf16*)take((size_t)M_ * 3 * D_ * 2);  // 48MB
    __bf16* ctxb  = (__bf16*)take((size_t)M_ * D_ * 2);      // 16MB
    __bf16* hb    = (__bf16*)take((size_t)M_ * D_ * 2);      // 16MB
    float*  tmp      = (float*)take((size_t)M_ * D_ * 4);
    float*  attn_out = (float*)take((size_t)M_ * D_ * 4);
    // aliases (regions dead by the time these are used):
    __bf16* hbuf = qkv;       // FFN hidden [M][4096] = 64MB over qkv+ctxb
    __bf16* vtg  = hb;        // hb dead after QKV GEMM; vtg dead after attn
    __bf16* attn_out_b = hb;  // written at ln1 (after attn)
    (void)in_sizes; (void)n_in; (void)out_size; (void)ws_size;

    // fused prep: 6 weight transposes + bias concat + hidden f2b
    prep_kernel<<<16396, 256, 0, stream>>>(
        Wq, Wk, Wv, Wo, Wi, Wo2, bq, bk, bv, hid,
        wqkvb, wob, wib, wo2b, qkvbias, hb);

    // fused QKV projection: [8192,1024] x [1024,3072]
    gemm_kernel<0><<<dim3(3*D_/128, M_/128), 256, 0, stream>>>(
        hb, wqkvb, qkvbias, nullptr, nullptr, qkv, M_, 3*D_, D_);

    // V -> vtg[b][h][d][s]
    dim3 tb(32, 8);
    vt_transpose_kernel<<<dim3(S_/32, H_*2, B_), tb, 0, stream>>>(qkv, vtg);

    // attn: flat 2048-block grid with XCD-locality remap inside the kernel
    attn_kernel<<<2048, 256, 0, stream>>>(qkv, vtg, mask, ctxb);

    // attn out projection + residual (fp32 hid) -> tmp
    gemm_kernel<1><<<dim3(D_/128, M_/128), 256, 0, stream>>>(
        ctxb, wob, bo, hid, tmp, nullptr, M_, D_, D_);
    ln_kernel<<<M_, 256, 0, stream>>>(tmp, g1, b1, attn_out, attn_out_b);

    // FFN
    gemm_kernel<2><<<dim3(DFF_/128, M_/128), 256, 0, stream>>>(
        attn_out_b, wib, bi, nullptr, nullptr, hbuf, M_, DFF_, D_);
    gemm_kernel<1><<<dim3(D_/128, M_/128), 256, 0, stream>>>(
        hbuf, wo2b, bo2, attn_out, tmp, nullptr, M_, D_, DFF_);
    ln_kernel<<<M_, 256, 0, stream>>>(tmp, g2, b2, out, nullptr);
}